// Round 14
// baseline (128.112 us; speedup 1.0000x reference)
//
#include <hip/hip_runtime.h>

#define NEG 0.01f
#define NBUCK_MAX 512   // buckets of 128 nodes; 50000/128 -> 391 used
#define CHUNK 4096      // edges per partition block
#define BCAP 3072       // fixed per-bucket capacity (mean 2046, +22 sigma)

typedef unsigned int uint;
typedef unsigned short ush;
typedef __attribute__((ext_vector_type(8))) short bf8v;            // 8 bf16 = 4 VGPRs
typedef __attribute__((ext_vector_type(8))) unsigned short us8v;   // 8 bf16 raw
typedef __attribute__((ext_vector_type(4))) float f4v;             // MFMA accumulator

__device__ __forceinline__ float bf2f(ush u) { return __uint_as_float(((uint)u) << 16); }
__device__ __forceinline__ ush f2bf(float f) {
  uint u = __float_as_uint(f);
  u += 0x7FFFu + ((u >> 16) & 1u);   // RNE
  return (ush)(u >> 16);
}

// ---------------- P0: zero bnext (hipMemsetAsync's in-graph fill cost ~40us) ----------------

__global__ void zero_kernel(int* __restrict__ p, int nwords) {
  int i = blockIdx.x * blockDim.x + threadIdx.x;
  if (i < nwords) p[i] = 0;
}

// edge record: (bucket<<23) | (src<<7) | dst_local   (src < 2^16, bucket < 512)

// ---------------- P1: partition edges into fixed-capacity bucket segments ----------------

__global__ __launch_bounds__(256) void partition_kernel(const int* __restrict__ src,
                                                        const int* __restrict__ dst,
                                                        int* __restrict__ bnext,
                                                        uint* __restrict__ tmp, int E) {
  __shared__ int hcnt[NBUCK_MAX];
  __shared__ int hbase[NBUCK_MAX];
  __shared__ int gbase[NBUCK_MAX];
  __shared__ int sc[256];
  __shared__ uint lrec[CHUNK];
  int t = threadIdx.x;
  for (int b = t; b < NBUCK_MAX; b += 256) hcnt[b] = 0;
  __syncthreads();
  int base = blockIdx.x * CHUNK;
  uint rec[CHUNK / 256];
  int slot[CHUNK / 256];
#pragma unroll
  for (int c = 0; c < CHUNK / 256; ++c) {
    int e = base + c * 256 + t;
    slot[c] = -1;
    if (e < E) {
      uint s = (uint)src[e], d = (uint)dst[e];
      uint b = d >> 7;
      rec[c] = (b << 23) | (s << 7) | (d & 127u);
      slot[c] = atomicAdd(&hcnt[b], 1);
    }
  }
  __syncthreads();
  int s0 = hcnt[2 * t], s1 = hcnt[2 * t + 1];
  int p = s0 + s1;
  sc[t] = p;
  __syncthreads();
  for (int off = 1; off < 256; off <<= 1) {
    int v = (t >= off) ? sc[t - off] : 0;
    __syncthreads();
    sc[t] += v;
    __syncthreads();
  }
  int ex = sc[t] - p;
  hbase[2 * t] = ex;
  hbase[2 * t + 1] = ex + s0;
  __syncthreads();
#pragma unroll
  for (int c = 0; c < CHUNK / 256; ++c) {
    if (slot[c] >= 0) lrec[hbase[rec[c] >> 23] + slot[c]] = rec[c];
  }
  for (int b = t; b < NBUCK_MAX; b += 256)
    if (hcnt[b]) gbase[b] = b * BCAP + atomicAdd(&bnext[b], hcnt[b]);
  __syncthreads();
  int m = min(CHUNK, E - base);
  for (int idx = t; idx < m; idx += 256) {
    uint r = lrec[idx];
    uint b = r >> 23;
    tmp[gbase[b] + (idx - hbase[b])] = r;
  }
}

// ---------------- P2: per-bucket finalize: rs/re, dinv, sorted col, xs ----------------

__global__ __launch_bounds__(256) void csr_finalize(const uint* __restrict__ tmp,
                                                    const int* __restrict__ bnext,
                                                    const float* __restrict__ x,
                                                    int* __restrict__ rs,
                                                    int* __restrict__ re,
                                                    float* __restrict__ dinv,
                                                    int* __restrict__ col,
                                                    ush* __restrict__ xs, int n) {
  __shared__ int lcnt[128];
  __shared__ int lnxt[128];
  __shared__ int lsc[128];
  __shared__ float ldi[128];
  __shared__ uint lcol[BCAP];
  int b = blockIdx.x;
  int t = threadIdx.x;
  int node0 = b << 7;
  int seg0 = b * BCAP;
  int m = min(bnext[b], BCAP);
  if (t < 128) lcnt[t] = 0;
  __syncthreads();
  for (int idx = t; idx < m; idx += 256)
    atomicAdd(&lcnt[tmp[seg0 + idx] & 127u], 1);
  __syncthreads();
  if (t < 128) lsc[t] = lcnt[t];
  __syncthreads();
  for (int off = 1; off < 128; off <<= 1) {
    int v = 0;
    if (t < 128 && t >= off) v = lsc[t - off];
    __syncthreads();
    if (t < 128) lsc[t] += v;
    __syncthreads();
  }
  if (t < 128) {
    int node = node0 + t;
    int ex = lsc[t] - lcnt[t];
    float di = rsqrtf((float)lcnt[t] + 1.0f);  // +1 self-loop
    ldi[t] = di;
    if (node < n) {
      rs[node] = seg0 + ex;
      re[node] = seg0 + ex + lcnt[t];
      dinv[node] = di;
    }
    lnxt[t] = ex;
  }
  __syncthreads();
  for (int idx = t; idx < m; idx += 256) {
    uint r = tmp[seg0 + idx];
    int p = atomicAdd(&lnxt[(int)(r & 127u)], 1);
    lcol[p] = (r >> 7) & 0xFFFFu;
  }
  __syncthreads();
  for (int idx = t; idx < m; idx += 256) col[seg0 + idx] = (int)lcol[idx];
  for (int idx = t; idx < 128 * 16; idx += 256) {
    int nl = idx >> 4, q = idx & 15;
    int node = node0 + nl;
    if (node < n) {
      float di = ldi[nl];
      float4 v = *(const float4*)&x[(size_t)node * 64 + q * 4];
      ushort4 o;
      o.x = f2bf(v.x * di);
      o.y = f2bf(v.y * di);
      o.z = f2bf(v.z * di);
      o.w = f2bf(v.w * di);
      *(ushort4*)&xs[(size_t)node * 64 + q * 4] = o;
    }
  }
}

// ---------------- Aggregation: 1 wave/node, 8 lanes x ushort8 (16B) per row ----------------

__global__ __launch_bounds__(256) void aggx_kernel(const ush* __restrict__ xs,
                                                   const float* __restrict__ dinv,
                                                   const int* __restrict__ rs,
                                                   const int* __restrict__ re,
                                                   const int* __restrict__ col,
                                                   ush* __restrict__ axs, int n) {
  int lane = threadIdx.x & 63;
  int g = lane >> 3, fl = lane & 7;
  int i = blockIdx.x * 4 + (threadIdx.x >> 6);
  if (i >= n) return;
  int e0 = rs[i], e1 = re[i];
  float a0[8] = {0.f, 0.f, 0.f, 0.f, 0.f, 0.f, 0.f, 0.f};
  float a1[8] = {0.f, 0.f, 0.f, 0.f, 0.f, 0.f, 0.f, 0.f};
  int e = e0;
  for (; e + 16 <= e1; e += 16) {
    int c0 = col[e + g], c1 = col[e + 8 + g];
    us8v u0 = *(const us8v*)&xs[(size_t)c0 * 64 + fl * 8];
    us8v u1 = *(const us8v*)&xs[(size_t)c1 * 64 + fl * 8];
#pragma unroll
    for (int q = 0; q < 8; ++q) a0[q] += bf2f(u0[q]);
#pragma unroll
    for (int q = 0; q < 8; ++q) a1[q] += bf2f(u1[q]);
  }
  for (; e < e1; e += 8) {
    int eg = e + g;
    bool valid = eg < e1;
    int c = col[valid ? eg : e];
    us8v u = *(const us8v*)&xs[(size_t)c * 64 + fl * 8];
    float msk = valid ? 1.f : 0.f;
#pragma unroll
    for (int q = 0; q < 8; ++q) a0[q] = fmaf(msk, bf2f(u[q]), a0[q]);
  }
#pragma unroll
  for (int q = 0; q < 8; ++q) a0[q] += a1[q];
#pragma unroll
  for (int q = 0; q < 8; ++q) a0[q] += __shfl_xor(a0[q], 8);
#pragma unroll
  for (int q = 0; q < 8; ++q) a0[q] += __shfl_xor(a0[q], 16);
#pragma unroll
  for (int q = 0; q < 8; ++q) a0[q] += __shfl_xor(a0[q], 32);
  if (g == 0) {
    us8v us = *(const us8v*)&xs[(size_t)i * 64 + fl * 8];
    float di = dinv[i];
    us8v o;
#pragma unroll
    for (int q = 0; q < 8; ++q) o[q] = f2bf(di * (a0[q] + bf2f(us[q])));
    *(us8v*)&axs[(size_t)i * 64 + fl * 8] = o;
  }
}

__global__ __launch_bounds__(256) void agg2_kernel(const ush* __restrict__ h2s,
                                                   const float* __restrict__ dinv,
                                                   const int* __restrict__ rs,
                                                   const int* __restrict__ re,
                                                   const int* __restrict__ col,
                                                   const float* __restrict__ bias,
                                                   const float* __restrict__ x,
                                                   float* __restrict__ out, int n) {
  int lane = threadIdx.x & 63;
  int g = lane >> 3, fl = lane & 7;
  int i = blockIdx.x * 4 + (threadIdx.x >> 6);
  if (i >= n) return;
  int e0 = rs[i], e1 = re[i];
  float a0[8] = {0.f, 0.f, 0.f, 0.f, 0.f, 0.f, 0.f, 0.f};
  float a1[8] = {0.f, 0.f, 0.f, 0.f, 0.f, 0.f, 0.f, 0.f};
  int e = e0;
  for (; e + 16 <= e1; e += 16) {
    int c0 = col[e + g], c1 = col[e + 8 + g];
    us8v u0 = *(const us8v*)&h2s[(size_t)c0 * 64 + fl * 8];
    us8v u1 = *(const us8v*)&h2s[(size_t)c1 * 64 + fl * 8];
#pragma unroll
    for (int q = 0; q < 8; ++q) a0[q] += bf2f(u0[q]);
#pragma unroll
    for (int q = 0; q < 8; ++q) a1[q] += bf2f(u1[q]);
  }
  for (; e < e1; e += 8) {
    int eg = e + g;
    bool valid = eg < e1;
    int c = col[valid ? eg : e];
    us8v u = *(const us8v*)&h2s[(size_t)c * 64 + fl * 8];
    float msk = valid ? 1.f : 0.f;
#pragma unroll
    for (int q = 0; q < 8; ++q) a0[q] = fmaf(msk, bf2f(u[q]), a0[q]);
  }
#pragma unroll
  for (int q = 0; q < 8; ++q) a0[q] += a1[q];
#pragma unroll
  for (int q = 0; q < 8; ++q) a0[q] += __shfl_xor(a0[q], 8);
#pragma unroll
  for (int q = 0; q < 8; ++q) a0[q] += __shfl_xor(a0[q], 16);
#pragma unroll
  for (int q = 0; q < 8; ++q) a0[q] += __shfl_xor(a0[q], 32);
  if (g == 0) {
    us8v us = *(const us8v*)&h2s[(size_t)i * 64 + fl * 8];
    float di = dinv[i];
    float4 xr0 = *(const float4*)&x[(size_t)i * 64 + fl * 8];
    float4 xr1 = *(const float4*)&x[(size_t)i * 64 + fl * 8 + 4];
    float4 bb0 = *(const float4*)&bias[fl * 8];
    float4 bb1 = *(const float4*)&bias[fl * 8 + 4];
    float4 o0, o1;
    o0.x = xr0.x + bb0.x + di * (a0[0] + bf2f(us[0]));
    o0.y = xr0.y + bb0.y + di * (a0[1] + bf2f(us[1]));
    o0.z = xr0.z + bb0.z + di * (a0[2] + bf2f(us[2]));
    o0.w = xr0.w + bb0.w + di * (a0[3] + bf2f(us[3]));
    o1.x = xr1.x + bb1.x + di * (a0[4] + bf2f(us[4]));
    o1.y = xr1.y + bb1.y + di * (a0[5] + bf2f(us[5]));
    o1.z = xr1.z + bb1.z + di * (a0[6] + bf2f(us[6]));
    o1.w = xr1.w + bb1.w + di * (a0[7] + bf2f(us[7]));
    *(float4*)&out[(size_t)i * 64 + fl * 8] = o0;
    *(float4*)&out[(size_t)i * 64 + fl * 8 + 4] = o1;
  }
}

// ---------------- GEMMs via MFMA; W staged from immutable d_in into LDS ----------------

#define P1 88    // w1 LDS row length in bf16
#define P2 136   // w2 LDS row length in bf16

// y1[n,128] = bf16( leaky(axs[n,64] @ W1 + b1) ); 1 tile/wave
__global__ __launch_bounds__(256) void gemm1_mfma(const ush* __restrict__ axs,
                                                  const float* __restrict__ W,
                                                  const float* __restrict__ b,
                                                  ush* __restrict__ y1, int n) {
  __shared__ ush wl[128 * P1];   // 22.5 KB
  int t = threadIdx.x;
  for (int idx = t; idx < 128 * 64; idx += 256) {
    int j = idx >> 6, k = idx & 63;
    wl[j * P1 + k] = f2bf(W[k * 128 + j]);
  }
  __syncthreads();
  int lane = t & 63;
  int m = lane & 15, kq = lane >> 4;
  int ntiles = (n + 15) >> 4;
  int wid = blockIdx.x * 4 + (t >> 6);
  if (wid >= ntiles) return;
  int node0 = wid << 4;
  int arow = min(node0 + m, n - 1);
  bf8v a0 = *(const bf8v*)&axs[(size_t)arow * 64 + kq * 8];
  bf8v a1 = *(const bf8v*)&axs[(size_t)arow * 64 + 32 + kq * 8];
#pragma unroll
  for (int j0 = 0; j0 < 128; j0 += 16) {
    const ush* wt = &wl[(j0 + m) * P1 + kq * 8];
    bf8v b0 = *(const bf8v*)wt;
    bf8v b1 = *(const bf8v*)(wt + 32);
    f4v acc = {0.f, 0.f, 0.f, 0.f};
    acc = __builtin_amdgcn_mfma_f32_16x16x32_bf16(a0, b0, acc, 0, 0, 0);
    acc = __builtin_amdgcn_mfma_f32_16x16x32_bf16(a1, b1, acc, 0, 0, 0);
    float bias = b[j0 + m];
#pragma unroll
    for (int r = 0; r < 4; ++r) {
      int orow = node0 + kq * 4 + r;
      if (orow < n) {
        float s = acc[r] + bias;
        s = (s >= 0.f) ? s : NEG * s;
        y1[(size_t)orow * 128 + j0 + m] = f2bf(s);
      }
    }
  }
}

// h2s[n,64] = bf16( dinv ⊙ (y1[n,128] @ W2) ); 1 tile/wave
__global__ __launch_bounds__(256) void gemm2_mfma(const ush* __restrict__ y1,
                                                  const float* __restrict__ W,
                                                  const float* __restrict__ dinv,
                                                  ush* __restrict__ h2s, int n) {
  __shared__ ush wl[64 * P2];   // 17.4 KB
  int t = threadIdx.x;
  for (int idx = t; idx < 64 * 128; idx += 256) {
    int j = idx >> 7, k = idx & 127;
    wl[j * P2 + k] = f2bf(W[k * 64 + j]);
  }
  __syncthreads();
  int lane = t & 63;
  int m = lane & 15, kq = lane >> 4;
  int ntiles = (n + 15) >> 4;
  int wid = blockIdx.x * 4 + (t >> 6);
  if (wid >= ntiles) return;
  int node0 = wid << 4;
  int arow = min(node0 + m, n - 1);
  const ush* ap = &y1[(size_t)arow * 128 + kq * 8];
  bf8v a0 = *(const bf8v*)(ap);
  bf8v a1 = *(const bf8v*)(ap + 32);
  bf8v a2 = *(const bf8v*)(ap + 64);
  bf8v a3 = *(const bf8v*)(ap + 96);
  float dv[4];
#pragma unroll
  for (int r = 0; r < 4; ++r) dv[r] = dinv[min(node0 + kq * 4 + r, n - 1)];
#pragma unroll
  for (int j0 = 0; j0 < 64; j0 += 16) {
    const ush* wt = &wl[(j0 + m) * P2 + kq * 8];
    f4v acc = {0.f, 0.f, 0.f, 0.f};
    acc = __builtin_amdgcn_mfma_f32_16x16x32_bf16(a0, *(const bf8v*)(wt), acc, 0, 0, 0);
    acc = __builtin_amdgcn_mfma_f32_16x16x32_bf16(a1, *(const bf8v*)(wt + 32), acc, 0, 0, 0);
    acc = __builtin_amdgcn_mfma_f32_16x16x32_bf16(a2, *(const bf8v*)(wt + 64), acc, 0, 0, 0);
    acc = __builtin_amdgcn_mfma_f32_16x16x32_bf16(a3, *(const bf8v*)(wt + 96), acc, 0, 0, 0);
#pragma unroll
    for (int r = 0; r < 4; ++r) {
      int orow = node0 + kq * 4 + r;
      if (orow < n) h2s[(size_t)orow * 64 + j0 + m] = f2bf(acc[r] * dv[r]);
    }
  }
}

// ---------------- launch ----------------

extern "C" void kernel_launch(void* const* d_in, const int* in_sizes, int n_in,
                              void* d_out, int out_size, void* d_ws, size_t ws_size,
                              hipStream_t stream) {
  const int n = in_sizes[0] / 64;   // 50000
  const int E = in_sizes[5] / 2;    // 800000

  const float* x  = (const float*)d_in[0];
  const float* W1 = (const float*)d_in[1];
  const float* b1 = (const float*)d_in[2];
  const float* W2 = (const float*)d_in[3];
  const float* b2 = (const float*)d_in[4];
  const int* edge = (const int*)d_in[5];
  const int* esrc = edge;
  const int* edst = edge + E;

  char* ws = (char*)d_ws;
  size_t o = 0;
  auto take = [&](size_t bytes) -> void* {
    void* p = ws + o;
    o += (bytes + 255) & ~(size_t)255;
    return p;
  };
  const int NBUCK = (n + 127) >> 7;  // 391
  int*   bnext   = (int*)take(NBUCK_MAX * 4);
  int*   rs      = (int*)take((size_t)n * 4);
  int*   re      = (int*)take((size_t)n * 4);
  float* dinv    = (float*)take((size_t)n * 4);
  uint*  tmp     = (uint*)take((size_t)NBUCK_MAX * BCAP * 4);
  int*   col     = (int*)take((size_t)NBUCK_MAX * BCAP * 4);
  ush*   xs      = (ush*)take((size_t)n * 64 * 2);
  ush*   axs     = (ush*)take((size_t)n * 64 * 2);
  ush*   y1      = (ush*)take((size_t)n * 128 * 2);
  ush*   h2s     = xs;  // xs dead after aggx; reuse

  zero_kernel<<<2, 256, 0, stream>>>(bnext, NBUCK_MAX);

  int pb = (E + CHUNK - 1) / CHUNK;  // 196
  partition_kernel<<<pb, 256, 0, stream>>>(esrc, edst, bnext, tmp, E);
  csr_finalize<<<NBUCK, 256, 0, stream>>>(tmp, bnext, x, rs, re, dinv, col, xs, n);

  aggx_kernel<<<(n + 3) / 4, 256, 0, stream>>>(xs, dinv, rs, re, col, axs, n);
  int gb = ((n + 15) / 16 + 3) / 4;  // 782: 1 tile per wave
  gemm1_mfma<<<gb, 256, 0, stream>>>(axs, W1, b1, y1, n);
  gemm2_mfma<<<gb, 256, 0, stream>>>(y1, W2, dinv, h2s, n);
  agg2_kernel<<<(n + 3) / 4, 256, 0, stream>>>(h2s, dinv, rs, re, col, b2, x,
                                               (float*)d_out, n);
}

// Round 15
// 120.068 us; speedup vs baseline: 1.0670x; 1.0670x over previous
//
#include <hip/hip_runtime.h>

#define NEG 0.01f
#define NBUCK_MAX 512   // buckets of 128 nodes; 50000/128 -> 391 used
#define CHUNK 4096      // edges per partition block
#define BCAP 3072       // fixed per-bucket capacity (mean 2046, +22 sigma)

typedef unsigned int uint;
typedef unsigned short ush;
typedef __attribute__((ext_vector_type(8))) short bf8v;            // 8 bf16 = 4 VGPRs
typedef __attribute__((ext_vector_type(8))) unsigned short us8v;   // 8 bf16 raw
typedef __attribute__((ext_vector_type(4))) float f4v;             // MFMA accumulator

__device__ __forceinline__ float bf2f(ush u) { return __uint_as_float(((uint)u) << 16); }
__device__ __forceinline__ ush f2bf(float f) {
  uint u = __float_as_uint(f);
  u += 0x7FFFu + ((u >> 16) & 1u);   // RNE
  return (ush)(u >> 16);
}

// ---------------- P0: zero bnext ----------------

__global__ void zero_kernel(int* __restrict__ p, int nwords) {
  int i = blockIdx.x * blockDim.x + threadIdx.x;
  if (i < nwords) p[i] = 0;
}

// edge record: (bucket<<23) | (src<<7) | dst_local   (src < 2^16, bucket < 512)

// ---------------- P1: partition edges into fixed-capacity bucket segments ----------------

__global__ __launch_bounds__(256) void partition_kernel(const int* __restrict__ src,
                                                        const int* __restrict__ dst,
                                                        int* __restrict__ bnext,
                                                        uint* __restrict__ tmp, int E) {
  __shared__ int hcnt[NBUCK_MAX];
  __shared__ int hbase[NBUCK_MAX];
  __shared__ int gbase[NBUCK_MAX];
  __shared__ int sc[256];
  __shared__ uint lrec[CHUNK];
  int t = threadIdx.x;
  for (int b = t; b < NBUCK_MAX; b += 256) hcnt[b] = 0;
  __syncthreads();
  int base = blockIdx.x * CHUNK;
  uint rec[CHUNK / 256];
  int slot[CHUNK / 256];
#pragma unroll
  for (int c = 0; c < CHUNK / 256; ++c) {
    int e = base + c * 256 + t;
    slot[c] = -1;
    if (e < E) {
      uint s = (uint)src[e], d = (uint)dst[e];
      uint b = d >> 7;
      rec[c] = (b << 23) | (s << 7) | (d & 127u);
      slot[c] = atomicAdd(&hcnt[b], 1);
    }
  }
  __syncthreads();
  int s0 = hcnt[2 * t], s1 = hcnt[2 * t + 1];
  int p = s0 + s1;
  sc[t] = p;
  __syncthreads();
  for (int off = 1; off < 256; off <<= 1) {
    int v = (t >= off) ? sc[t - off] : 0;
    __syncthreads();
    sc[t] += v;
    __syncthreads();
  }
  int ex = sc[t] - p;
  hbase[2 * t] = ex;
  hbase[2 * t + 1] = ex + s0;
  __syncthreads();
#pragma unroll
  for (int c = 0; c < CHUNK / 256; ++c) {
    if (slot[c] >= 0) lrec[hbase[rec[c] >> 23] + slot[c]] = rec[c];
  }
  for (int b = t; b < NBUCK_MAX; b += 256)
    if (hcnt[b]) gbase[b] = b * BCAP + atomicAdd(&bnext[b], hcnt[b]);
  __syncthreads();
  int m = min(CHUNK, E - base);
  for (int idx = t; idx < m; idx += 256) {
    uint r = lrec[idx];
    uint b = r >> 23;
    tmp[gbase[b] + (idx - hbase[b])] = r;
  }
}

// ---------------- P2: per-bucket finalize: rs/re, dinv, sorted col, xs ----------------

__global__ __launch_bounds__(256) void csr_finalize(const uint* __restrict__ tmp,
                                                    const int* __restrict__ bnext,
                                                    const float* __restrict__ x,
                                                    int* __restrict__ rs,
                                                    int* __restrict__ re,
                                                    float* __restrict__ dinv,
                                                    int* __restrict__ col,
                                                    ush* __restrict__ xs, int n) {
  __shared__ int lcnt[128];
  __shared__ int lnxt[128];
  __shared__ int lsc[128];
  __shared__ float ldi[128];
  __shared__ uint lcol[BCAP];
  int b = blockIdx.x;
  int t = threadIdx.x;
  int node0 = b << 7;
  int seg0 = b * BCAP;
  int m = min(bnext[b], BCAP);
  if (t < 128) lcnt[t] = 0;
  __syncthreads();
  for (int idx = t; idx < m; idx += 256)
    atomicAdd(&lcnt[tmp[seg0 + idx] & 127u], 1);
  __syncthreads();
  if (t < 128) lsc[t] = lcnt[t];
  __syncthreads();
  for (int off = 1; off < 128; off <<= 1) {
    int v = 0;
    if (t < 128 && t >= off) v = lsc[t - off];
    __syncthreads();
    if (t < 128) lsc[t] += v;
    __syncthreads();
  }
  if (t < 128) {
    int node = node0 + t;
    int ex = lsc[t] - lcnt[t];
    float di = rsqrtf((float)lcnt[t] + 1.0f);  // +1 self-loop
    ldi[t] = di;
    if (node < n) {
      rs[node] = seg0 + ex;
      re[node] = seg0 + ex + lcnt[t];
      dinv[node] = di;
    }
    lnxt[t] = ex;
  }
  __syncthreads();
  for (int idx = t; idx < m; idx += 256) {
    uint r = tmp[seg0 + idx];
    int p = atomicAdd(&lnxt[(int)(r & 127u)], 1);
    lcol[p] = (r >> 7) & 0xFFFFu;
  }
  __syncthreads();
  for (int idx = t; idx < m; idx += 256) col[seg0 + idx] = (int)lcol[idx];
  for (int idx = t; idx < 128 * 16; idx += 256) {
    int nl = idx >> 4, q = idx & 15;
    int node = node0 + nl;
    if (node < n) {
      float di = ldi[nl];
      float4 v = *(const float4*)&x[(size_t)node * 64 + q * 4];
      ushort4 o;
      o.x = f2bf(v.x * di);
      o.y = f2bf(v.y * di);
      o.z = f2bf(v.z * di);
      o.w = f2bf(v.w * di);
      *(ushort4*)&xs[(size_t)node * 64 + q * 4] = o;
    }
  }
}

// ---------------- Aggregation: 1 wave/node, 8 lanes x ushort8; uniform 2-deep masked loop ----------------

__global__ __launch_bounds__(256) void aggx_kernel(const ush* __restrict__ xs,
                                                   const float* __restrict__ dinv,
                                                   const int* __restrict__ rs,
                                                   const int* __restrict__ re,
                                                   const int* __restrict__ col,
                                                   ush* __restrict__ axs, int n) {
  int lane = threadIdx.x & 63;
  int g = lane >> 3, fl = lane & 7;
  int i = blockIdx.x * 4 + (threadIdx.x >> 6);
  if (i >= n) return;
  int e0 = rs[i], e1 = re[i];
  float a0[8] = {0.f, 0.f, 0.f, 0.f, 0.f, 0.f, 0.f, 0.f};
  float a1[8] = {0.f, 0.f, 0.f, 0.f, 0.f, 0.f, 0.f, 0.f};
  for (int e = e0; e < e1; e += 16) {   // every round: 16 gathers in flight
    int i0 = e + g, i1 = e + 8 + g;
    bool v0 = i0 < e1, v1 = i1 < e1;
    int c0 = col[v0 ? i0 : e0];
    int c1 = col[v1 ? i1 : e0];
    float m0 = v0 ? 1.f : 0.f, m1 = v1 ? 1.f : 0.f;
    us8v u0 = *(const us8v*)&xs[(size_t)c0 * 64 + fl * 8];
    us8v u1 = *(const us8v*)&xs[(size_t)c1 * 64 + fl * 8];
#pragma unroll
    for (int q = 0; q < 8; ++q) a0[q] = fmaf(m0, bf2f(u0[q]), a0[q]);
#pragma unroll
    for (int q = 0; q < 8; ++q) a1[q] = fmaf(m1, bf2f(u1[q]), a1[q]);
  }
#pragma unroll
  for (int q = 0; q < 8; ++q) a0[q] += a1[q];
#pragma unroll
  for (int q = 0; q < 8; ++q) a0[q] += __shfl_xor(a0[q], 8);
#pragma unroll
  for (int q = 0; q < 8; ++q) a0[q] += __shfl_xor(a0[q], 16);
#pragma unroll
  for (int q = 0; q < 8; ++q) a0[q] += __shfl_xor(a0[q], 32);
  if (g == 0) {
    us8v us = *(const us8v*)&xs[(size_t)i * 64 + fl * 8];
    float di = dinv[i];
    us8v o;
#pragma unroll
    for (int q = 0; q < 8; ++q) o[q] = f2bf(di * (a0[q] + bf2f(us[q])));
    *(us8v*)&axs[(size_t)i * 64 + fl * 8] = o;
  }
}

__global__ __launch_bounds__(256) void agg2_kernel(const ush* __restrict__ h2s,
                                                   const float* __restrict__ dinv,
                                                   const int* __restrict__ rs,
                                                   const int* __restrict__ re,
                                                   const int* __restrict__ col,
                                                   const float* __restrict__ bias,
                                                   const float* __restrict__ x,
                                                   float* __restrict__ out, int n) {
  int lane = threadIdx.x & 63;
  int g = lane >> 3, fl = lane & 7;
  int i = blockIdx.x * 4 + (threadIdx.x >> 6);
  if (i >= n) return;
  int e0 = rs[i], e1 = re[i];
  float a0[8] = {0.f, 0.f, 0.f, 0.f, 0.f, 0.f, 0.f, 0.f};
  float a1[8] = {0.f, 0.f, 0.f, 0.f, 0.f, 0.f, 0.f, 0.f};
  for (int e = e0; e < e1; e += 16) {
    int i0 = e + g, i1 = e + 8 + g;
    bool v0 = i0 < e1, v1 = i1 < e1;
    int c0 = col[v0 ? i0 : e0];
    int c1 = col[v1 ? i1 : e0];
    float m0 = v0 ? 1.f : 0.f, m1 = v1 ? 1.f : 0.f;
    us8v u0 = *(const us8v*)&h2s[(size_t)c0 * 64 + fl * 8];
    us8v u1 = *(const us8v*)&h2s[(size_t)c1 * 64 + fl * 8];
#pragma unroll
    for (int q = 0; q < 8; ++q) a0[q] = fmaf(m0, bf2f(u0[q]), a0[q]);
#pragma unroll
    for (int q = 0; q < 8; ++q) a1[q] = fmaf(m1, bf2f(u1[q]), a1[q]);
  }
#pragma unroll
  for (int q = 0; q < 8; ++q) a0[q] += a1[q];
#pragma unroll
  for (int q = 0; q < 8; ++q) a0[q] += __shfl_xor(a0[q], 8);
#pragma unroll
  for (int q = 0; q < 8; ++q) a0[q] += __shfl_xor(a0[q], 16);
#pragma unroll
  for (int q = 0; q < 8; ++q) a0[q] += __shfl_xor(a0[q], 32);
  if (g == 0) {
    us8v us = *(const us8v*)&h2s[(size_t)i * 64 + fl * 8];
    float di = dinv[i];
    float4 xr0 = *(const float4*)&x[(size_t)i * 64 + fl * 8];
    float4 xr1 = *(const float4*)&x[(size_t)i * 64 + fl * 8 + 4];
    float4 bb0 = *(const float4*)&bias[fl * 8];
    float4 bb1 = *(const float4*)&bias[fl * 8 + 4];
    float4 o0, o1;
    o0.x = xr0.x + bb0.x + di * (a0[0] + bf2f(us[0]));
    o0.y = xr0.y + bb0.y + di * (a0[1] + bf2f(us[1]));
    o0.z = xr0.z + bb0.z + di * (a0[2] + bf2f(us[2]));
    o0.w = xr0.w + bb0.w + di * (a0[3] + bf2f(us[3]));
    o1.x = xr1.x + bb1.x + di * (a0[4] + bf2f(us[4]));
    o1.y = xr1.y + bb1.y + di * (a0[5] + bf2f(us[5]));
    o1.z = xr1.z + bb1.z + di * (a0[6] + bf2f(us[6]));
    o1.w = xr1.w + bb1.w + di * (a0[7] + bf2f(us[7]));
    *(float4*)&out[(size_t)i * 64 + fl * 8] = o0;
    *(float4*)&out[(size_t)i * 64 + fl * 8 + 4] = o1;
  }
}

// ---------------- Fused GEMM (R13 structure, slimmer LDS: 53.2KB -> 3 blocks/CU) ----------------
// gemm1 swapped-operand: D holds y1^T fragments -> packed ds_write_b64 into per-wave tile;
// gemm2 reads tile rows back as A-frags. All row strides 16B-multiples for b128 alignment.

#define P1 72    // w1 LDS row (64+8 bf16; 144B stride: 2-way banks, b128-aligned)
#define P2 136   // w2 LDS row (128+8; 272B stride, b128-aligned)
#define PY 136   // y1 tile row (272B stride, b128-aligned)

__global__ __launch_bounds__(256) void gemm_fused(const ush* __restrict__ axs,
                                                  const float* __restrict__ W1,
                                                  const float* __restrict__ b1,
                                                  const float* __restrict__ W2,
                                                  const float* __restrict__ dinv,
                                                  ush* __restrict__ h2s, int n) {
  __shared__ ush wl1[128 * P1];     // 18.4 KB: wl1[j][k] = W1[k][j]
  __shared__ ush wl2[64 * P2];      // 17.4 KB: wl2[j][k] = W2[k][j]
  __shared__ ush y1t[4][16][PY];    // 17.4 KB: per-wave y1 tile, row-major
  int t = threadIdx.x;
  for (int idx = t; idx < 128 * 64; idx += 256) {
    int j = idx >> 6, k = idx & 63;
    wl1[j * P1 + k] = f2bf(W1[k * 128 + j]);
  }
  for (int idx = t; idx < 64 * 128; idx += 256) {
    int j = idx >> 7, k = idx & 127;
    wl2[j * P2 + k] = f2bf(W2[k * 64 + j]);
  }
  __syncthreads();
  int w = t >> 6, lane = t & 63;
  int m = lane & 15, kq = lane >> 4;
  int ntiles = (n + 15) >> 4;
  int wid = min(blockIdx.x * 4 + w, ntiles - 1);   // clamp: duplicate waves rewrite same data
  int node0 = wid << 4;
  int arow = min(node0 + m, n - 1);
  bf8v a0 = *(const bf8v*)&axs[(size_t)arow * 64 + kq * 8];
  bf8v a1 = *(const bf8v*)&axs[(size_t)arow * 64 + 32 + kq * 8];
  // ---- gemm1 transposed: D = W1^T-tile (A) x axs-frag (B) ----
#pragma unroll
  for (int jt = 0; jt < 8; ++jt) {
    const ush* wt = &wl1[(jt * 16 + m) * P1 + kq * 8];
    bf8v w0 = *(const bf8v*)wt;
    bf8v w1 = *(const bf8v*)(wt + 32);
    f4v acc = {0.f, 0.f, 0.f, 0.f};
    acc = __builtin_amdgcn_mfma_f32_16x16x32_bf16(w0, a0, acc, 0, 0, 0);
    acc = __builtin_amdgcn_mfma_f32_16x16x32_bf16(w1, a1, acc, 0, 0, 0);
    float4 bb = *(const float4*)&b1[jt * 16 + kq * 4];
    float bv[4] = {bb.x, bb.y, bb.z, bb.w};
    ush h[4];
#pragma unroll
    for (int r = 0; r < 4; ++r) {
      float s = acc[r] + bv[r];
      s = (s >= 0.f) ? s : NEG * s;
      h[r] = f2bf(s);
    }
    uint2 pk;
    pk.x = (uint)h[0] | ((uint)h[1] << 16);
    pk.y = (uint)h[2] | ((uint)h[3] << 16);
    *(uint2*)&y1t[w][m][jt * 16 + kq * 4] = pk;   // row m, 4 consecutive cols
  }
  // ---- gemm2: A-frags from same-wave LDS y1 tile (lgkmcnt orders) ----
  const ush* yrow = &y1t[w][m][0];
  bf8v c0 = *(const bf8v*)&yrow[kq * 8];
  bf8v c1 = *(const bf8v*)&yrow[32 + kq * 8];
  bf8v c2 = *(const bf8v*)&yrow[64 + kq * 8];
  bf8v c3 = *(const bf8v*)&yrow[96 + kq * 8];
  float dv[4];
#pragma unroll
  for (int r = 0; r < 4; ++r) dv[r] = dinv[min(node0 + kq * 4 + r, n - 1)];
#pragma unroll
  for (int j0 = 0; j0 < 64; j0 += 16) {
    const ush* wt = &wl2[(j0 + m) * P2 + kq * 8];
    f4v acc = {0.f, 0.f, 0.f, 0.f};
    acc = __builtin_amdgcn_mfma_f32_16x16x32_bf16(c0, *(const bf8v*)(wt), acc, 0, 0, 0);
    acc = __builtin_amdgcn_mfma_f32_16x16x32_bf16(c1, *(const bf8v*)(wt + 32), acc, 0, 0, 0);
    acc = __builtin_amdgcn_mfma_f32_16x16x32_bf16(c2, *(const bf8v*)(wt + 64), acc, 0, 0, 0);
    acc = __builtin_amdgcn_mfma_f32_16x16x32_bf16(c3, *(const bf8v*)(wt + 96), acc, 0, 0, 0);
#pragma unroll
    for (int r = 0; r < 4; ++r) {
      int orow = node0 + kq * 4 + r;
      if (orow < n) h2s[(size_t)orow * 64 + j0 + m] = f2bf(acc[r] * dv[r]);
    }
  }
}

// ---------------- launch ----------------

extern "C" void kernel_launch(void* const* d_in, const int* in_sizes, int n_in,
                              void* d_out, int out_size, void* d_ws, size_t ws_size,
                              hipStream_t stream) {
  const int n = in_sizes[0] / 64;   // 50000
  const int E = in_sizes[5] / 2;    // 800000

  const float* x  = (const float*)d_in[0];
  const float* W1 = (const float*)d_in[1];
  const float* b1 = (const float*)d_in[2];
  const float* W2 = (const float*)d_in[3];
  const float* b2 = (const float*)d_in[4];
  const int* edge = (const int*)d_in[5];
  const int* esrc = edge;
  const int* edst = edge + E;

  char* ws = (char*)d_ws;
  size_t o = 0;
  auto take = [&](size_t bytes) -> void* {
    void* p = ws + o;
    o += (bytes + 255) & ~(size_t)255;
    return p;
  };
  const int NBUCK = (n + 127) >> 7;  // 391
  int*   bnext   = (int*)take(NBUCK_MAX * 4);
  int*   rs      = (int*)take((size_t)n * 4);
  int*   re      = (int*)take((size_t)n * 4);
  float* dinv    = (float*)take((size_t)n * 4);
  uint*  tmp     = (uint*)take((size_t)NBUCK_MAX * BCAP * 4);
  int*   col     = (int*)take((size_t)NBUCK_MAX * BCAP * 4);
  ush*   xs      = (ush*)take((size_t)n * 64 * 2);
  ush*   axs     = (ush*)take((size_t)n * 64 * 2);
  ush*   h2s     = xs;  // xs dead after aggx; reuse

  zero_kernel<<<2, 256, 0, stream>>>(bnext, NBUCK_MAX);

  int pb = (E + CHUNK - 1) / CHUNK;  // 196
  partition_kernel<<<pb, 256, 0, stream>>>(esrc, edst, bnext, tmp, E);
  csr_finalize<<<NBUCK, 256, 0, stream>>>(tmp, bnext, x, rs, re, dinv, col, xs, n);

  aggx_kernel<<<(n + 3) / 4, 256, 0, stream>>>(xs, dinv, rs, re, col, axs, n);
  int gb = ((n + 15) / 16 + 3) / 4;  // 782: 1 tile per wave (excess waves clamp)
  gemm_fused<<<gb, 256, 0, stream>>>(axs, W1, b1, W2, dinv, h2s, n);
  agg2_kernel<<<(n + 3) / 4, 256, 0, stream>>>(h2s, dinv, rs, re, col, b2, x,
                                               (float*)d_out, n);
}